// Round 5
// baseline (987.773 us; speedup 1.0000x reference)
//
#include <hip/hip_runtime.h>
#include <hip/hip_bf16.h>
#include <cstddef>

// Problem constants
#define BB 4
#define KK 32      // KMOD
#define TTT 64     // T
#define NNC 128    // N
#define GG4 512    // 4N
// ws layout (floats):
//   X    [4][32][64][128]            = 1048576
//   h    [inst][b][s][256]           = 2097152
//   red2 [4][256][2]                 = 2048     (per-WG GroupNorm partials)
//   pre  [bid][st(scan order)][512]  = 8388608  (gate dim permuted: u*4+gate)

__device__ __forceinline__ float sigm(float x) { return 1.f / (1.f + __expf(-x)); }
__device__ __forceinline__ float tanh_fast(float x) {
    x = fminf(fmaxf(x, -15.f), 15.f);
    float e = __expf(2.f * x);
    return (e - 1.f) / (e + 1.f);
}

// copy x -> X and emit GroupNorm partials. 1024 blocks x 256 thr, 1 float4/thr.
__global__ void k_copy_red(const float4* __restrict__ src, float4* __restrict__ dst,
                           float* __restrict__ red2) {
    const int i = blockIdx.x * 256 + threadIdx.x;
    const float4 v = src[i];
    dst[i] = v;
    float s  = v.x + v.y + v.z + v.w;
    float ss = v.x * v.x + v.y * v.y + v.z * v.z + v.w * v.w;
    for (int off = 32; off; off >>= 1) {
        s  += __shfl_down(s, off);
        ss += __shfl_down(ss, off);
    }
    __shared__ float l0[4], l1[4];
    const int w = threadIdx.x >> 6;
    if ((threadIdx.x & 63) == 0) { l0[w] = s; l1[w] = ss; }
    __syncthreads();
    if (threadIdx.x == 0) {
        const int b = blockIdx.x >> 8, slot = blockIdx.x & 255;
        red2[(b * 256 + slot) * 2]     = l0[0] + l0[1] + l0[2] + l0[3];
        red2[(b * 256 + slot) * 2 + 1] = l1[0] + l1[1] + l1[2] + l1[3];
    }
}

// ---------------------------------------------------------------------------
// k_pre: GroupNorm-apply + input projection. WG per (inst, dir, b); 1024 thr
// = (gate row g in [0,512), half hh in {0,1}); 64-float half-row in 16 float4.
// Output written in SCAN ORDER with gate dim permuted to u*4+gate.
// ---------------------------------------------------------------------------
template <bool BAND>
__global__ __launch_bounds__(1024, 1) void k_pre(
    const float* __restrict__ X, float* __restrict__ pre,
    const float* __restrict__ red2,
    const float* __restrict__ w_ih,
    const float* __restrict__ b_ih, const float* __restrict__ b_hh,
    const float* __restrict__ gn_g, const float* __restrict__ gn_b,
    int layer)
{
    constexpr int S    = BAND ? 32 : 64;
    constexpr int INST = BAND ? 64 : 32;
    const int tid = threadIdx.x;
    const int g   = tid & 511;
    const int hh  = tid >> 9;
    const int bid = blockIdx.x;
    const int b = bid & 3, dir = (bid >> 2) & 1, inst = bid >> 3;

    __shared__ float xn[S * 128];
    __shared__ float ex[4][1024];
    __shared__ float biasl[512];

    // mean / rstd from per-WG partials
    float s0 = 0.f, s1 = 0.f;
    {
        const float* rp = red2 + b * 512;
#pragma unroll 8
        for (int i = 0; i < 512; i += 2) { s0 += rp[i]; s1 += rp[i + 1]; }
    }
    const float mu = s0 * (1.0f / 262144.0f);
    const float rs = rsqrtf(fmaxf(s1 * (1.0f / 262144.0f) - mu * mu, 0.f) + 1e-5f);

    const size_t wbase = ((size_t)layer * INST + inst) * 2 + dir;
    if (tid < 512) biasl[tid] = b_ih[wbase * 512 + tid] + b_hh[wbase * 512 + tid];

    // normalize this WG's x-slice into LDS
    {
        const size_t xbase = BAND ? ((size_t)b * 2048 + inst) * 128
                                  : ((size_t)b * 32 + inst) * 64 * 128;
        const float* gmg = gn_g + layer * 128;
        const float* gmb = gn_b + layer * 128;
        for (int i4 = tid; i4 < S * 32; i4 += 1024) {
            int srow = i4 >> 5, n4 = i4 & 31;
            const float4 v = *(const float4*)(X + xbase +
                              (BAND ? (size_t)srow * 8192 : (size_t)srow * 128) + n4 * 4);
            const float4 ga = *(const float4*)(gmg + n4 * 4);
            const float4 be = *(const float4*)(gmb + n4 * 4);
            float4 o;
            o.x = (v.x - mu) * rs * ga.x + be.x;
            o.y = (v.y - mu) * rs * ga.y + be.y;
            o.z = (v.z - mu) * rs * ga.z + be.z;
            o.w = (v.w - mu) * rs * ga.w + be.w;
            *(float4*)(xn + srow * 128 + n4 * 4) = o;
        }
    }

    // half-row of w_ih: 16 float4 (64 VGPR), statically indexed
    float4 w4[16];
    {
        const float* wr = w_ih + (wbase * 512 + g) * 128 + hh * 64;
#pragma unroll
        for (int j = 0; j < 16; ++j) w4[j] = *(const float4*)(wr + 4 * j);
    }
    __syncthreads();

    float* pb = pre + (size_t)bid * (S * 512);
    for (int st0 = 0; st0 < S; st0 += 4) {
#pragma unroll
        for (int q = 0; q < 4; ++q) {
            const int st = st0 + q;
            const int sidx = dir ? (S - 1 - st) : st;
            const float* xr = xn + sidx * 128 + hh * 64;   // wave-uniform -> broadcast
            float a0 = 0.f, a1 = 0.f, a2 = 0.f, a3 = 0.f;
#pragma unroll
            for (int j = 0; j < 4; ++j) {
                float4 hv0 = *(const float4*)(xr + 16 * j);
                float4 hv1 = *(const float4*)(xr + 16 * j + 4);
                float4 hv2 = *(const float4*)(xr + 16 * j + 8);
                float4 hv3 = *(const float4*)(xr + 16 * j + 12);
                a0 += w4[4*j].x   * hv0.x + w4[4*j].y   * hv0.y + w4[4*j].z   * hv0.z + w4[4*j].w   * hv0.w;
                a1 += w4[4*j+1].x * hv1.x + w4[4*j+1].y * hv1.y + w4[4*j+1].z * hv1.z + w4[4*j+1].w * hv1.w;
                a2 += w4[4*j+2].x * hv2.x + w4[4*j+2].y * hv2.y + w4[4*j+2].z * hv2.z + w4[4*j+2].w * hv2.w;
                a3 += w4[4*j+3].x * hv3.x + w4[4*j+3].y * hv3.y + w4[4*j+3].z * hv3.z + w4[4*j+3].w * hv3.w;
            }
            ex[q][hh * 512 + g] = (a0 + a1) + (a2 + a3);
        }
        __syncthreads();
        for (int idx = tid; idx < 4 * 512; idx += 1024) {
            const int q = idx >> 9, gg = idx & 511;
            const int u = gg & 127, gt = gg >> 7;
            pb[(size_t)(st0 + q) * 512 + u * 4 + gt] =
                ex[q][gg] + ex[q][512 + gg] + biasl[gg];
        }
        __syncthreads();
    }
}

// ---------------------------------------------------------------------------
// k_scan3: recurrence, one barrier per step. WG per (inst, dir, b); 1024 thr
// = (unit u in [0,128), sub j in [0,8)). Lane holds 4 gates x 16 cols of w_hh
// (64 VGPR). Per step: 4x16 FMA -> 3x shfl_xor (in-wave) -> all 8 lanes
// redundantly compute gates -> j==0 writes h (double-buffered LDS) -> barrier.
// ---------------------------------------------------------------------------
template <bool BAND>
__global__ __launch_bounds__(1024, 1) void k_scan3(
    const float* __restrict__ pre, float* __restrict__ hout,
    const float* __restrict__ w_hh, int layer)
{
    constexpr int S    = BAND ? 32 : 64;
    constexpr int INST = BAND ? 64 : 32;
    constexpr int CH   = 8;
    constexpr int NCH  = S / CH;
    const int tid = threadIdx.x;
    const int u   = tid >> 3;
    const int j   = tid & 7;
    const int bid = blockIdx.x;
    const int b = bid & 3, dir = (bid >> 2) & 1, inst = bid >> 3;

    __shared__ float plds[2][CH * 512];
    __shared__ float hbuf[2][128];

    const size_t wbase = ((size_t)layer * INST + inst) * 2 + dir;
    float4 w4[4][4];
    {
        const float* wb = w_hh + wbase * 512 * 128;
#pragma unroll
        for (int gt = 0; gt < 4; ++gt) {
            const float* wr = wb + (size_t)(gt * 128 + u) * 128 + j * 16;
#pragma unroll
            for (int k = 0; k < 4; ++k) w4[gt][k] = *(const float4*)(wr + 4 * k);
        }
    }

    const float* pb = pre + (size_t)bid * (S * 512);
    ((float4*)plds[0])[tid] = ((const float4*)pb)[tid];      // chunk 0
    if (tid < 256) ((float*)hbuf)[tid] = 0.f;
    __syncthreads();

    float c = 0.f;
    float* hob = hout + (((size_t)inst * 4 + b) * S) * 256 + dir * 128;

    int cur = 0;
    float4 pf;
    for (int ch = 0; ch < NCH; ++ch) {
        const int buf = ch & 1;
        if (ch + 1 < NCH)
            pf = ((const float4*)(pb + (size_t)(ch + 1) * CH * 512))[tid];  // prefetch
#pragma unroll
        for (int q = 0; q < CH; ++q) {
            const float* hr = &hbuf[cur][j * 16];
            const float4 hv0 = *(const float4*)(hr);
            const float4 hv1 = *(const float4*)(hr + 4);
            const float4 hv2 = *(const float4*)(hr + 8);
            const float4 hv3 = *(const float4*)(hr + 12);
            float acc0, acc1, acc2, acc3;
            {
                float a;
                a  = w4[0][0].x*hv0.x + w4[0][0].y*hv0.y + w4[0][0].z*hv0.z + w4[0][0].w*hv0.w;
                a += w4[0][1].x*hv1.x + w4[0][1].y*hv1.y + w4[0][1].z*hv1.z + w4[0][1].w*hv1.w;
                a += w4[0][2].x*hv2.x + w4[0][2].y*hv2.y + w4[0][2].z*hv2.z + w4[0][2].w*hv2.w;
                a += w4[0][3].x*hv3.x + w4[0][3].y*hv3.y + w4[0][3].z*hv3.z + w4[0][3].w*hv3.w;
                acc0 = a;
                a  = w4[1][0].x*hv0.x + w4[1][0].y*hv0.y + w4[1][0].z*hv0.z + w4[1][0].w*hv0.w;
                a += w4[1][1].x*hv1.x + w4[1][1].y*hv1.y + w4[1][1].z*hv1.z + w4[1][1].w*hv1.w;
                a += w4[1][2].x*hv2.x + w4[1][2].y*hv2.y + w4[1][2].z*hv2.z + w4[1][2].w*hv2.w;
                a += w4[1][3].x*hv3.x + w4[1][3].y*hv3.y + w4[1][3].z*hv3.z + w4[1][3].w*hv3.w;
                acc1 = a;
                a  = w4[2][0].x*hv0.x + w4[2][0].y*hv0.y + w4[2][0].z*hv0.z + w4[2][0].w*hv0.w;
                a += w4[2][1].x*hv1.x + w4[2][1].y*hv1.y + w4[2][1].z*hv1.z + w4[2][1].w*hv1.w;
                a += w4[2][2].x*hv2.x + w4[2][2].y*hv2.y + w4[2][2].z*hv2.z + w4[2][2].w*hv2.w;
                a += w4[2][3].x*hv3.x + w4[2][3].y*hv3.y + w4[2][3].z*hv3.z + w4[2][3].w*hv3.w;
                acc2 = a;
                a  = w4[3][0].x*hv0.x + w4[3][0].y*hv0.y + w4[3][0].z*hv0.z + w4[3][0].w*hv0.w;
                a += w4[3][1].x*hv1.x + w4[3][1].y*hv1.y + w4[3][1].z*hv1.z + w4[3][1].w*hv1.w;
                a += w4[3][2].x*hv2.x + w4[3][2].y*hv2.y + w4[3][2].z*hv2.z + w4[3][2].w*hv2.w;
                a += w4[3][3].x*hv3.x + w4[3][3].y*hv3.y + w4[3][3].z*hv3.z + w4[3][3].w*hv3.w;
                acc3 = a;
            }
#pragma unroll
            for (int off = 1; off < 8; off <<= 1) {
                acc0 += __shfl_xor(acc0, off);
                acc1 += __shfl_xor(acc1, off);
                acc2 += __shfl_xor(acc2, off);
                acc3 += __shfl_xor(acc3, off);
            }
            const float4 p4 = *(const float4*)&plds[buf][q * 512 + u * 4];
            const float gi = acc0 + p4.x;
            const float gf = acc1 + p4.y;
            const float gG = acc2 + p4.z;
            const float go = acc3 + p4.w;
            c = sigm(gf) * c + sigm(gi) * tanh_fast(gG);
            const float hval = sigm(go) * tanh_fast(c);
            const int nxt = cur ^ 1;
            if (j == 0) {
                hbuf[nxt][u] = hval;
                const int st = ch * CH + q;
                const int sidx = dir ? (S - 1 - st) : st;
                hob[(size_t)sidx * 256 + u] = hval;
            }
            if (q == CH - 1 && ch + 1 < NCH)
                ((float4*)plds[buf ^ 1])[tid] = pf;
            __syncthreads();
            cur = nxt;
        }
    }
}

// FC (h[2N] -> N) + bias + residual into X; emits next module's GroupNorm
// partials; final module also writes the sliced output. 1024 WGs x 256 thr.
template <bool BAND>
__global__ void k_fc(const float* __restrict__ h, const float* __restrict__ fc_w,
                     const float* __restrict__ fc_b, float* __restrict__ X,
                     float* __restrict__ red2, float* __restrict__ out,
                     int layer, int final_out)
{
    constexpr int S    = BAND ? 32 : 64;
    constexpr int INST = BAND ? 64 : 32;
    constexpr int RPB  = 8;                       // rows per block
    constexpr int CPB  = S / RPB;                 // chunks per batch
    const int inst  = blockIdx.x / (BB * CPB);
    const int chunk = blockIdx.x % (BB * CPB);

    __shared__ float hs[RPB * 256];
    const int tid = threadIdx.x;
    const float* hbase = h + ((size_t)inst * BB * S + chunk * RPB) * 256;
    for (int i = tid; i < RPB * 64; i += 256)
        ((float4*)hs)[i] = ((const float4*)hbase)[i];
    __syncthreads();

    const int n  = tid & 127;
    const int rg = tid >> 7;                      // 0..1 -> rows rg*4 .. rg*4+3
    const float* wrow = fc_w + (((size_t)layer * INST + inst) * 128 + n) * 256;
    float4 a0 = {0,0,0,0}, a1 = {0,0,0,0}, a2 = {0,0,0,0}, a3 = {0,0,0,0};
#pragma unroll 8
    for (int d4 = 0; d4 < 64; ++d4) {
        float4 wv = ((const float4*)wrow)[d4];
        float4 h0 = ((const float4*)(hs + (rg * 4 + 0) * 256))[d4];
        float4 h1 = ((const float4*)(hs + (rg * 4 + 1) * 256))[d4];
        float4 h2 = ((const float4*)(hs + (rg * 4 + 2) * 256))[d4];
        float4 h3 = ((const float4*)(hs + (rg * 4 + 3) * 256))[d4];
        a0.x += wv.x*h0.x; a0.y += wv.y*h0.y; a0.z += wv.z*h0.z; a0.w += wv.w*h0.w;
        a1.x += wv.x*h1.x; a1.y += wv.y*h1.y; a1.z += wv.z*h1.z; a1.w += wv.w*h1.w;
        a2.x += wv.x*h2.x; a2.y += wv.y*h2.y; a2.z += wv.z*h2.z; a2.w += wv.w*h2.w;
        a3.x += wv.x*h3.x; a3.y += wv.y*h3.y; a3.z += wv.z*h3.z; a3.w += wv.w*h3.w;
    }
    const float bias = fc_b[((size_t)layer * INST + inst) * 128 + n];
    float acc[4];
    acc[0] = (a0.x + a0.y) + (a0.z + a0.w);
    acc[1] = (a1.x + a1.y) + (a1.z + a1.w);
    acc[2] = (a2.x + a2.y) + (a2.z + a2.w);
    acc[3] = (a3.x + a3.y) + (a3.z + a3.w);

    float s = 0.f, ss = 0.f;
#pragma unroll
    for (int i = 0; i < 4; ++i) {
        const int r = chunk * RPB + rg * 4 + i;
        const int b = r / S, sd = r % S;
        const size_t xi = BAND ? (((size_t)b * 32 + sd) * 64 + inst) * 128 + n
                               : (((size_t)b * 32 + inst) * 64 + sd) * 128 + n;
        const float v = X[xi] + acc[i] + bias;
        X[xi] = v;
        s += v; ss += v * v;
        if (BAND && final_out && sd < 30)
            out[(((size_t)b * 30 + sd) * 64 + inst) * 128 + n] = v;
    }
    // per-WG GroupNorm partials for the next module
    for (int off = 32; off; off >>= 1) {
        s  += __shfl_down(s, off);
        ss += __shfl_down(ss, off);
    }
    __shared__ float l0[4], l1[4];
    const int w = tid >> 6;
    if ((tid & 63) == 0) { l0[w] = s; l1[w] = ss; }
    __syncthreads();
    if (tid == 0) {
        const int bsel = chunk / CPB;
        const int slot = inst * CPB + (chunk % CPB);
        red2[(bsel * 256 + slot) * 2]     = l0[0] + l0[1] + l0[2] + l0[3];
        red2[(bsel * 256 + slot) * 2 + 1] = l1[0] + l1[1] + l1[2] + l1[3];
    }
}

extern "C" void kernel_launch(void* const* d_in, const int* in_sizes, int n_in,
                              void* d_out, int out_size, void* d_ws, size_t ws_size,
                              hipStream_t stream) {
    const float* x     = (const float*)d_in[0];
    const float* tw_ih = (const float*)d_in[1];
    const float* tw_hh = (const float*)d_in[2];
    const float* tb_ih = (const float*)d_in[3];
    const float* tb_hh = (const float*)d_in[4];
    const float* tfc_w = (const float*)d_in[5];
    const float* tfc_b = (const float*)d_in[6];
    const float* tgn_g = (const float*)d_in[7];
    const float* tgn_b = (const float*)d_in[8];
    const float* bw_ih = (const float*)d_in[9];
    const float* bw_hh = (const float*)d_in[10];
    const float* bb_ih = (const float*)d_in[11];
    const float* bb_hh = (const float*)d_in[12];
    const float* bfc_w = (const float*)d_in[13];
    const float* bfc_b = (const float*)d_in[14];
    const float* bgn_g = (const float*)d_in[15];
    const float* bgn_b = (const float*)d_in[16];

    float* X    = (float*)d_ws;                // 1048576 floats
    float* h    = X + 1048576;                 // 2097152 floats
    float* red2 = h + 2097152;                 // 2048 floats
    float* pre  = red2 + 2048;                 // 8388608 floats
    float* out  = (float*)d_out;

    k_copy_red<<<1024, 256, 0, stream>>>((const float4*)x, (float4*)X, red2);

    for (int layer = 0; layer < 2; ++layer) {
        // temporal module (per-band LSTM over T)
        k_pre<false><<<256, 1024, 0, stream>>>(X, pre, red2, tw_ih, tb_ih, tb_hh,
                                               tgn_g, tgn_b, layer);
        k_scan3<false><<<256, 1024, 0, stream>>>(pre, h, tw_hh, layer);
        k_fc<false><<<1024, 256, 0, stream>>>(h, tfc_w, tfc_b, X, red2, out, layer, 0);
        // band module (per-frame LSTM over K)
        k_pre<true><<<512, 1024, 0, stream>>>(X, pre, red2, bw_ih, bb_ih, bb_hh,
                                              bgn_g, bgn_b, layer);
        k_scan3<true><<<512, 1024, 0, stream>>>(pre, h, bw_hh, layer);
        k_fc<true><<<1024, 256, 0, stream>>>(h, bfc_w, bfc_b, X, red2, out,
                                             layer, layer == 1 ? 1 : 0);
    }
}